// Round 2
// baseline (1355.815 us; speedup 1.0000x reference)
//
#include <hip/hip_runtime.h>

// UpSampling: out[row][0:N] = 0, out[row][N+e] = 0.5*(data[row][e0] + data[row][e1])
// rows = B*C = 512, N = 100000, E = 200000, all f32.

constexpr int B_ = 4, C_ = 128, N_ = 100000, E_ = 200000;
constexpr int ROWS = B_ * C_;            // 512
constexpr long long W = N_ + E_;         // 300000 floats per output row
constexpr int NQ = N_ / 4;               // 25000 float4 zero-stores per row
constexpr int EQ = E_ / 4;               // 50000 quad-edge units per row
constexpr int ZBX = (NQ + 255) / 256;    // 98 blocks for zero head
constexpr int MBX = (EQ + 255) / 256;    // 196 blocks for mids

typedef float  vf4 __attribute__((ext_vector_type(4)));  // clang vector: ok for nontemporal builtins
typedef int    vi4 __attribute__((ext_vector_type(4)));

__global__ __launch_bounds__(256) void upsample_kernel(
    const float* __restrict__ data,
    const vi4*   __restrict__ e4,     // edges as int4: 2 edges per vi4
    float*       __restrict__ out)
{
    const int row = blockIdx.y;
    float* __restrict__ orow = out + (size_t)row * (size_t)W;

    if (blockIdx.x < ZBX) {
        // zero-fill head: N floats = NQ float4s (N % 4 == 0, row offsets 16B-aligned)
        int q = blockIdx.x * 256 + threadIdx.x;
        if (q < NQ) {
            vf4 z = (vf4)(0.f);
            __builtin_nontemporal_store(z, ((vf4*)orow) + q);
        }
    } else {
        // mids: 4 edges per thread -> 8 gathers -> 1 float4 store
        int q = (blockIdx.x - ZBX) * 256 + threadIdx.x;
        if (q < EQ) {
            const float* __restrict__ drow = data + (size_t)row * (size_t)N_;
            vi4 a = e4[2 * q];
            vi4 b = e4[2 * q + 1];
            vf4 m;
            m.x = 0.5f * (drow[a.x] + drow[a.y]);
            m.y = 0.5f * (drow[a.z] + drow[a.w]);
            m.z = 0.5f * (drow[b.x] + drow[b.y]);
            m.w = 0.5f * (drow[b.z] + drow[b.w]);
            __builtin_nontemporal_store(m, (vf4*)(orow + N_) + q);
        }
    }
}

extern "C" void kernel_launch(void* const* d_in, const int* in_sizes, int n_in,
                              void* d_out, int out_size, void* d_ws, size_t ws_size,
                              hipStream_t stream) {
    const float* data  = (const float*)d_in[0];
    const vi4*   edges = (const vi4*)d_in[1];
    float*       out   = (float*)d_out;

    dim3 grid(ZBX + MBX, ROWS);
    upsample_kernel<<<grid, 256, 0, stream>>>(data, edges, out);
}